// Round 1
// baseline (316.239 us; speedup 1.0000x reference)
//
#include <hip/hip_runtime.h>

// ---------------------------------------------------------------------------
// 2-layer GAT on MI355X.
// Pipeline:
//   1. CSR build by dst: hist -> block scan -> scan of block sums -> finalize
//      -> scatter (src ids grouped by dst).  int32 atomics only.
//   2. k_gemm1: xh1 = x @ W1^T  [N,128], fused a_s1/a_d1 = <xh1, att>  [N,2]
//   3. k_agg1 : one wave per node, online softmax over in-edges, writes
//               h = relu(agg + b1)  [N,128]
//   4. k_gemm2: xh2 = h @ W2^T  [N,64], fused a_s2/a_d2  [N,1]
//   5. k_agg2 : one wave per node, online softmax, + b2, row L2-normalize,
//               writes d_out [N,64]
// No float atomics anywhere; per-node accumulators live in registers.
// ---------------------------------------------------------------------------

__global__ void k_hist(const int* __restrict__ dst_e, int n_edges, int n_loops,
                       int* __restrict__ deg) {
    int i = blockIdx.x * blockDim.x + threadIdx.x;
    int tot = n_edges + n_loops;
    if (i >= tot) return;
    int d = (i < n_edges) ? dst_e[i] : (i - n_edges);   // self-loops appended
    atomicAdd(&deg[d], 1);
}

// inclusive scan of deg within 1024-blocks -> offs (inclusive), block totals
__global__ void k_scan1(const int* __restrict__ deg, int* __restrict__ offs,
                        int* __restrict__ bsums, int n) {
    __shared__ int sm[1024];
    int tid = threadIdx.x;
    int i = blockIdx.x * 1024 + tid;
    int v = (i < n) ? deg[i] : 0;
    sm[tid] = v;
    __syncthreads();
    for (int off = 1; off < 1024; off <<= 1) {
        int t = (tid >= off) ? sm[tid - off] : 0;
        __syncthreads();
        sm[tid] += t;
        __syncthreads();
    }
    if (i < n) offs[i] = sm[tid];
    if (tid == 1023) bsums[blockIdx.x] = sm[1023];
}

// exclusive scan of <=64 block sums (N=50000 -> 49 blocks) in one wave
__global__ void k_scan2(int* __restrict__ bsums, int nb) {
    int l = threadIdx.x;  // block of 64 = one wave
    int v = (l < nb) ? bsums[l] : 0;
    int orig = v;
    for (int off = 1; off < 64; off <<= 1) {
        int u = __shfl_up(v, off, 64);
        if (l >= off) v += u;
    }
    if (l < nb) bsums[l] = v - orig;  // exclusive
}

// offs: inclusive -> exclusive (+ block offset); init cursor; offs[n] = total
__global__ void k_scan3(const int* __restrict__ deg, int* __restrict__ offs,
                        int* __restrict__ cursor, const int* __restrict__ bsums,
                        int n, int total) {
    int i = blockIdx.x * blockDim.x + threadIdx.x;
    if (i < n) {
        int e = offs[i] - deg[i] + bsums[i >> 10];
        offs[i] = e;
        cursor[i] = e;
    }
    if (i == n) offs[n] = total;
}

__global__ void k_scatter(const int* __restrict__ src_e, const int* __restrict__ dst_e,
                          int n_edges, int n_loops, int* __restrict__ cursor,
                          int* __restrict__ csr_src) {
    int i = blockIdx.x * blockDim.x + threadIdx.x;
    int tot = n_edges + n_loops;
    if (i >= tot) return;
    int s = (i < n_edges) ? src_e[i] : (i - n_edges);
    int d = (i < n_edges) ? dst_e[i] : (i - n_edges);
    int pos = atomicAdd(&cursor[d], 1);
    csr_src[pos] = s;
}

// xh1 = x @ W1^T  (N x 128 @ 128 x 128), fused attention dots.
// 256 thr: tx=t&31 -> cols 4tx..4tx+3, ty=t>>5 -> rows ty+8i (i<4). 32 rows/blk.
__global__ __launch_bounds__(256) void k_gemm1(
    const float* __restrict__ x, const float* __restrict__ W,
    const float* __restrict__ att_s, const float* __restrict__ att_d,
    float* __restrict__ xh, float* __restrict__ as_, float* __restrict__ ad_,
    int n) {
    __shared__ float xs[32][128];
    __shared__ float wt[32][132];  // [kk][col], padded: stride 132 kills bank conflicts
    int t = threadIdx.x;
    int tx = t & 31;
    int ty = t >> 5;
    int row0 = blockIdx.x * 32;

    for (int i = 0; i < 16; i++) {  // 32*128 elems, 16/thread, coalesced
        int flat = i * 256 + t;
        int r = flat >> 7, k = flat & 127;
        int rr = row0 + r;
        xs[r][k] = (rr < n) ? x[rr * 128 + k] : 0.0f;
    }

    float acc[4][4];
#pragma unroll
    for (int i = 0; i < 4; i++)
#pragma unroll
        for (int j = 0; j < 4; j++) acc[i][j] = 0.f;

    for (int kb = 0; kb < 4; kb++) {
        __syncthreads();
        for (int i = 0; i < 16; i++) {  // W chunk [32kk][128c]
            int flat = i * 256 + t;
            int kk = flat & 31, c = flat >> 5;
            wt[kk][c] = W[c * 128 + kb * 32 + kk];
        }
        __syncthreads();
#pragma unroll 8
        for (int kk = 0; kk < 32; kk++) {
            float4 w = *(const float4*)&wt[kk][tx * 4];
#pragma unroll
            for (int i = 0; i < 4; i++) {
                float xv = xs[ty + 8 * i][kb * 32 + kk];
                acc[i][0] += xv * w.x;
                acc[i][1] += xv * w.y;
                acc[i][2] += xv * w.z;
                acc[i][3] += xv * w.w;
            }
        }
    }

    float asv[4], adv[4];
#pragma unroll
    for (int j = 0; j < 4; j++) {
        asv[j] = att_s[tx * 4 + j];
        adv[j] = att_d[tx * 4 + j];
    }
#pragma unroll
    for (int i = 0; i < 4; i++) {
        int row = row0 + ty + 8 * i;
        float ps = 0.f, pd = 0.f;
#pragma unroll
        for (int j = 0; j < 4; j++) {
            ps += acc[i][j] * asv[j];
            pd += acc[i][j] * adv[j];
        }
        // lanes 0..15 of each 16-group cover one head's 64 cols
        for (int off = 1; off < 16; off <<= 1) {
            ps += __shfl_xor(ps, off, 64);
            pd += __shfl_xor(pd, off, 64);
        }
        if (row < n) {
            float4 o = make_float4(acc[i][0], acc[i][1], acc[i][2], acc[i][3]);
            *(float4*)&xh[row * 128 + tx * 4] = o;
            if ((tx & 15) == 0) {
                int head = tx >> 4;  // tx in {0,16}
                as_[row * 2 + head] = ps;
                ad_[row * 2 + head] = pd;
            }
        }
    }
}

// xh2 = h @ W2^T (N x 128 @ 128 x 64). tx=t&15 -> cols 4tx..4tx+3, ty=t>>4,
// rows ty+16i (i<2). 32 rows/blk.
__global__ __launch_bounds__(256) void k_gemm2(
    const float* __restrict__ h, const float* __restrict__ W,
    const float* __restrict__ att_s, const float* __restrict__ att_d,
    float* __restrict__ xh, float* __restrict__ as_, float* __restrict__ ad_,
    int n) {
    __shared__ float xs[32][128];
    __shared__ float wt[32][68];
    int t = threadIdx.x;
    int tx = t & 15;
    int ty = t >> 4;
    int row0 = blockIdx.x * 32;

    for (int i = 0; i < 16; i++) {
        int flat = i * 256 + t;
        int r = flat >> 7, k = flat & 127;
        int rr = row0 + r;
        xs[r][k] = (rr < n) ? h[rr * 128 + k] : 0.0f;
    }

    float acc[2][4];
#pragma unroll
    for (int i = 0; i < 2; i++)
#pragma unroll
        for (int j = 0; j < 4; j++) acc[i][j] = 0.f;

    for (int kb = 0; kb < 4; kb++) {
        __syncthreads();
        for (int i = 0; i < 8; i++) {  // 32*64 elems
            int flat = i * 256 + t;
            int kk = flat & 31, c = flat >> 5;
            wt[kk][c] = W[c * 128 + kb * 32 + kk];
        }
        __syncthreads();
#pragma unroll 8
        for (int kk = 0; kk < 32; kk++) {
            float4 w = *(const float4*)&wt[kk][tx * 4];
#pragma unroll
            for (int i = 0; i < 2; i++) {
                float xv = xs[ty + 16 * i][kb * 32 + kk];
                acc[i][0] += xv * w.x;
                acc[i][1] += xv * w.y;
                acc[i][2] += xv * w.z;
                acc[i][3] += xv * w.w;
            }
        }
    }

    float asv[4], adv[4];
#pragma unroll
    for (int j = 0; j < 4; j++) {
        asv[j] = att_s[tx * 4 + j];
        adv[j] = att_d[tx * 4 + j];
    }
#pragma unroll
    for (int i = 0; i < 2; i++) {
        int row = row0 + ty + 16 * i;
        float ps = 0.f, pd = 0.f;
#pragma unroll
        for (int j = 0; j < 4; j++) {
            ps += acc[i][j] * asv[j];
            pd += acc[i][j] * adv[j];
        }
        for (int off = 1; off < 16; off <<= 1) {  // 16 lanes = all 64 cols
            ps += __shfl_xor(ps, off, 64);
            pd += __shfl_xor(pd, off, 64);
        }
        if (row < n) {
            float4 o = make_float4(acc[i][0], acc[i][1], acc[i][2], acc[i][3]);
            *(float4*)&xh[row * 64 + tx * 4] = o;
            if (tx == 0) {
                as_[row] = ps;
                ad_[row] = pd;
            }
        }
    }
}

// Layer-1 aggregation: one wave per node; lane l owns channels 2l,2l+1
// (head = l>>5). Online softmax over in-edges; writes h = relu(agg + b).
__global__ __launch_bounds__(256) void k_agg1(
    const float* __restrict__ xh, const float* __restrict__ as_,
    const float* __restrict__ ad_, const int* __restrict__ offs,
    const int* __restrict__ csr_src, const float* __restrict__ bias,
    float* __restrict__ hout, int n) {
    int node = blockIdx.x * 4 + (threadIdx.x >> 6);
    if (node >= n) return;
    int l = threadIdx.x & 63;
    int c0 = l * 2;
    int head = l >> 5;
    float ad = ad_[node * 2 + head];
    int beg = offs[node], end = offs[node + 1];

    float m = -1e30f, s = 0.f, a0 = 0.f, a1 = 0.f;
    for (int base = beg; base < end; base += 64) {
        int cnt = min(64, end - base);
        int sv = (l < cnt) ? csr_src[base + l] : 0;
        for (int j = 0; j < cnt; j++) {
            int si = __shfl(sv, j, 64);
            float2 asv = *(const float2*)&as_[si * 2];
            float a = (head ? asv.y : asv.x) + ad;
            a = (a > 0.f) ? a : 0.2f * a;          // leaky_relu(0.2)
            float mn = fmaxf(m, a);
            float sc = __expf(m - mn);
            float p = __expf(a - mn);
            float2 xv = *(const float2*)&xh[si * 128 + c0];
            s = s * sc + p;
            a0 = a0 * sc + p * xv.x;
            a1 = a1 * sc + p * xv.y;
            m = mn;
        }
    }
    float inv = 1.0f / (s + 1e-16f);
    float o0 = fmaxf(a0 * inv + bias[c0], 0.f);
    float o1 = fmaxf(a1 * inv + bias[c0 + 1], 0.f);
    *(float2*)&hout[node * 128 + c0] = make_float2(o0, o1);
}

// Layer-2 aggregation + bias + row L2-normalize. Lane l owns channel l.
__global__ __launch_bounds__(256) void k_agg2(
    const float* __restrict__ xh, const float* __restrict__ as_,
    const float* __restrict__ ad_, const int* __restrict__ offs,
    const int* __restrict__ csr_src, const float* __restrict__ bias,
    float* __restrict__ out, int n) {
    int node = blockIdx.x * 4 + (threadIdx.x >> 6);
    if (node >= n) return;
    int l = threadIdx.x & 63;
    float ad = ad_[node];
    int beg = offs[node], end = offs[node + 1];

    float m = -1e30f, s = 0.f, acc = 0.f;
    for (int base = beg; base < end; base += 64) {
        int cnt = min(64, end - base);
        int sv = (l < cnt) ? csr_src[base + l] : 0;
        for (int j = 0; j < cnt; j++) {
            int si = __shfl(sv, j, 64);
            float a = as_[si] + ad;
            a = (a > 0.f) ? a : 0.2f * a;
            float mn = fmaxf(m, a);
            float sc = __expf(m - mn);
            float p = __expf(a - mn);
            float xv = xh[si * 64 + l];
            s = s * sc + p;
            acc = acc * sc + p * xv;
            m = mn;
        }
    }
    float o = acc / (s + 1e-16f) + bias[l];
    float sq = o * o;
    for (int off = 32; off; off >>= 1) sq += __shfl_xor(sq, off, 64);
    float nrm = sqrtf(sq);
    out[node * 64 + l] = o / fmaxf(nrm, 1e-12f);
}

extern "C" void kernel_launch(void* const* d_in, const int* in_sizes, int n_in,
                              void* d_out, int out_size, void* d_ws, size_t ws_size,
                              hipStream_t stream) {
    const float* x   = (const float*)d_in[0];
    const int*   ei  = (const int*)d_in[1];   // [2,E] int32: row0=src, row1=dst
    const float* W1  = (const float*)d_in[2];
    const float* as1 = (const float*)d_in[3];
    const float* ad1 = (const float*)d_in[4];
    const float* b1  = (const float*)d_in[5];
    const float* W2  = (const float*)d_in[6];
    const float* as2 = (const float*)d_in[7];
    const float* ad2 = (const float*)d_in[8];
    const float* b2  = (const float*)d_in[9];
    float* out = (float*)d_out;

    const int N  = in_sizes[0] / 128;
    const int E  = in_sizes[1] / 2;
    const int ET = E + N;   // edges + self-loops

    char* ws = (char*)d_ws;
    size_t off = 0;
    auto alloc = [&](size_t bytes) -> char* {
        char* p = ws + off;
        off = (off + bytes + 255) & ~size_t(255);
        return p;
    };
    float* xh1   = (float*)alloc((size_t)N * 128 * 4);
    float* hbuf  = (float*)alloc((size_t)N * 128 * 4);
    float* xh2   = (float*)alloc((size_t)N * 64 * 4);
    float* a_s1  = (float*)alloc((size_t)N * 2 * 4);
    float* a_d1  = (float*)alloc((size_t)N * 2 * 4);
    float* a_s2  = (float*)alloc((size_t)N * 4);
    float* a_d2  = (float*)alloc((size_t)N * 4);
    int*   deg   = (int*)alloc((size_t)N * 4);
    int*   offs  = (int*)alloc((size_t)(N + 1) * 4);
    int*   curs  = (int*)alloc((size_t)N * 4);
    int*   bsums = (int*)alloc(64 * 4);
    int*   csr   = (int*)alloc((size_t)ET * 4);

    hipMemsetAsync(deg, 0, (size_t)N * 4, stream);

    int gE = (ET + 255) / 256;
    k_hist<<<gE, 256, 0, stream>>>(ei + E, E, N, deg);

    int nb = (N + 1023) / 1024;  // 49 for N=50000 (k_scan2 handles <=64)
    k_scan1<<<nb, 1024, 0, stream>>>(deg, offs, bsums, N);
    k_scan2<<<1, 64, 0, stream>>>(bsums, nb);
    k_scan3<<<(N + 1 + 255) / 256, 256, 0, stream>>>(deg, offs, curs, bsums, N, ET);
    k_scatter<<<gE, 256, 0, stream>>>(ei, ei + E, E, N, curs, csr);

    k_gemm1<<<(N + 31) / 32, 256, 0, stream>>>(x, W1, as1, ad1, xh1, a_s1, a_d1, N);
    k_agg1<<<(N + 3) / 4, 256, 0, stream>>>(xh1, a_s1, a_d1, offs, csr, b1, hbuf, N);
    k_gemm2<<<(N + 31) / 32, 256, 0, stream>>>(hbuf, W2, as2, ad2, xh2, a_s2, a_d2, N);
    k_agg2<<<(N + 3) / 4, 256, 0, stream>>>(xh2, a_s2, a_d2, offs, csr, b2, out, N);
}

// Round 2
// 288.258 us; speedup vs baseline: 1.0971x; 1.0971x over previous
//
#include <hip/hip_runtime.h>
#include <hip/hip_fp16.h>

// ---------------------------------------------------------------------------
// 2-layer GAT on MI355X, round 2.
//   CSR build (int atomics) ->
//   k_gemm1: xh1=x@W1^T (store fp16) + attention dots (from fp32 acc)
//   k_att1 : per-node lane-parallel softmax -> normalized edge weights w1[E,2]
//   k_agg1 : pure weighted segment-sum of fp16 xh1, 4-deep ILP, + bias + relu
//   k_gemm2/k_att2/k_agg2: same for layer 2 (+ L2 row normalize)
// ---------------------------------------------------------------------------

__global__ void k_hist(const int* __restrict__ dst_e, int n_edges, int n_loops,
                       int* __restrict__ deg) {
    int i = blockIdx.x * blockDim.x + threadIdx.x;
    int tot = n_edges + n_loops;
    if (i >= tot) return;
    int d = (i < n_edges) ? dst_e[i] : (i - n_edges);
    atomicAdd(&deg[d], 1);
}

__global__ void k_scan1(const int* __restrict__ deg, int* __restrict__ offs,
                        int* __restrict__ bsums, int n) {
    __shared__ int sm[1024];
    int tid = threadIdx.x;
    int i = blockIdx.x * 1024 + tid;
    int v = (i < n) ? deg[i] : 0;
    sm[tid] = v;
    __syncthreads();
    for (int off = 1; off < 1024; off <<= 1) {
        int t = (tid >= off) ? sm[tid - off] : 0;
        __syncthreads();
        sm[tid] += t;
        __syncthreads();
    }
    if (i < n) offs[i] = sm[tid];
    if (tid == 1023) bsums[blockIdx.x] = sm[1023];
}

__global__ void k_scan2(int* __restrict__ bsums, int nb) {
    int l = threadIdx.x;
    int v = (l < nb) ? bsums[l] : 0;
    int orig = v;
    for (int off = 1; off < 64; off <<= 1) {
        int u = __shfl_up(v, off, 64);
        if (l >= off) v += u;
    }
    if (l < nb) bsums[l] = v - orig;
}

__global__ void k_scan3(const int* __restrict__ deg, int* __restrict__ offs,
                        int* __restrict__ cursor, const int* __restrict__ bsums,
                        int n, int total) {
    int i = blockIdx.x * blockDim.x + threadIdx.x;
    if (i < n) {
        int e = offs[i] - deg[i] + bsums[i >> 10];
        offs[i] = e;
        cursor[i] = e;
    }
    if (i == n) offs[n] = total;
}

__global__ void k_scatter(const int* __restrict__ src_e, const int* __restrict__ dst_e,
                          int n_edges, int n_loops, int* __restrict__ cursor,
                          int* __restrict__ csr_src) {
    int i = blockIdx.x * blockDim.x + threadIdx.x;
    int tot = n_edges + n_loops;
    if (i >= tot) return;
    int s = (i < n_edges) ? src_e[i] : (i - n_edges);
    int d = (i < n_edges) ? dst_e[i] : (i - n_edges);
    int pos = atomicAdd(&cursor[d], 1);
    csr_src[pos] = s;
}

// xh1 = x @ W1^T (N x 128 @ 128 x 128) -> fp16; fused attention dots (fp32).
__global__ __launch_bounds__(256) void k_gemm1(
    const float* __restrict__ x, const float* __restrict__ W,
    const float* __restrict__ att_s, const float* __restrict__ att_d,
    __half* __restrict__ xh, float* __restrict__ as_, float* __restrict__ ad_,
    int n) {
    __shared__ float xs[32][128];
    __shared__ float wt[32][132];
    int t = threadIdx.x;
    int tx = t & 31;
    int ty = t >> 5;
    int row0 = blockIdx.x * 32;

    for (int i = 0; i < 16; i++) {
        int flat = i * 256 + t;
        int r = flat >> 7, k = flat & 127;
        int rr = row0 + r;
        xs[r][k] = (rr < n) ? x[rr * 128 + k] : 0.0f;
    }

    float acc[4][4];
#pragma unroll
    for (int i = 0; i < 4; i++)
#pragma unroll
        for (int j = 0; j < 4; j++) acc[i][j] = 0.f;

    for (int kb = 0; kb < 4; kb++) {
        __syncthreads();
        for (int i = 0; i < 16; i++) {
            int flat = i * 256 + t;
            int kk = flat & 31, c = flat >> 5;
            wt[kk][c] = W[c * 128 + kb * 32 + kk];
        }
        __syncthreads();
#pragma unroll 8
        for (int kk = 0; kk < 32; kk++) {
            float4 w = *(const float4*)&wt[kk][tx * 4];
#pragma unroll
            for (int i = 0; i < 4; i++) {
                float xv = xs[ty + 8 * i][kb * 32 + kk];
                acc[i][0] += xv * w.x;
                acc[i][1] += xv * w.y;
                acc[i][2] += xv * w.z;
                acc[i][3] += xv * w.w;
            }
        }
    }

    float asv[4], adv[4];
#pragma unroll
    for (int j = 0; j < 4; j++) {
        asv[j] = att_s[tx * 4 + j];
        adv[j] = att_d[tx * 4 + j];
    }
#pragma unroll
    for (int i = 0; i < 4; i++) {
        int row = row0 + ty + 8 * i;
        float ps = 0.f, pd = 0.f;
#pragma unroll
        for (int j = 0; j < 4; j++) {
            ps += acc[i][j] * asv[j];
            pd += acc[i][j] * adv[j];
        }
        for (int off = 1; off < 16; off <<= 1) {
            ps += __shfl_xor(ps, off, 64);
            pd += __shfl_xor(pd, off, 64);
        }
        if (row < n) {
            __half2 p0 = __floats2half2_rn(acc[i][0], acc[i][1]);
            __half2 p1 = __floats2half2_rn(acc[i][2], acc[i][3]);
            ((__half2*)xh)[row * 64 + tx * 2]     = p0;
            ((__half2*)xh)[row * 64 + tx * 2 + 1] = p1;
            if ((tx & 15) == 0) {
                int head = tx >> 4;
                as_[row * 2 + head] = ps;
                ad_[row * 2 + head] = pd;
            }
        }
    }
}

// xh2 = h @ W2^T (N x 128 @ 128 x 64) -> fp16; fused attention dots.
__global__ __launch_bounds__(256) void k_gemm2(
    const float* __restrict__ h, const float* __restrict__ W,
    const float* __restrict__ att_s, const float* __restrict__ att_d,
    __half* __restrict__ xh, float* __restrict__ as_, float* __restrict__ ad_,
    int n) {
    __shared__ float xs[32][128];
    __shared__ float wt[32][68];
    int t = threadIdx.x;
    int tx = t & 15;
    int ty = t >> 4;
    int row0 = blockIdx.x * 32;

    for (int i = 0; i < 16; i++) {
        int flat = i * 256 + t;
        int r = flat >> 7, k = flat & 127;
        int rr = row0 + r;
        xs[r][k] = (rr < n) ? h[rr * 128 + k] : 0.0f;
    }

    float acc[2][4];
#pragma unroll
    for (int i = 0; i < 2; i++)
#pragma unroll
        for (int j = 0; j < 4; j++) acc[i][j] = 0.f;

    for (int kb = 0; kb < 4; kb++) {
        __syncthreads();
        for (int i = 0; i < 8; i++) {
            int flat = i * 256 + t;
            int kk = flat & 31, c = flat >> 5;
            wt[kk][c] = W[c * 128 + kb * 32 + kk];
        }
        __syncthreads();
#pragma unroll 8
        for (int kk = 0; kk < 32; kk++) {
            float4 w = *(const float4*)&wt[kk][tx * 4];
#pragma unroll
            for (int i = 0; i < 2; i++) {
                float xv = xs[ty + 16 * i][kb * 32 + kk];
                acc[i][0] += xv * w.x;
                acc[i][1] += xv * w.y;
                acc[i][2] += xv * w.z;
                acc[i][3] += xv * w.w;
            }
        }
    }

    float asv[4], adv[4];
#pragma unroll
    for (int j = 0; j < 4; j++) {
        asv[j] = att_s[tx * 4 + j];
        adv[j] = att_d[tx * 4 + j];
    }
#pragma unroll
    for (int i = 0; i < 2; i++) {
        int row = row0 + ty + 16 * i;
        float ps = 0.f, pd = 0.f;
#pragma unroll
        for (int j = 0; j < 4; j++) {
            ps += acc[i][j] * asv[j];
            pd += acc[i][j] * adv[j];
        }
        for (int off = 1; off < 16; off <<= 1) {
            ps += __shfl_xor(ps, off, 64);
            pd += __shfl_xor(pd, off, 64);
        }
        if (row < n) {
            __half2 p0 = __floats2half2_rn(acc[i][0], acc[i][1]);
            __half2 p1 = __floats2half2_rn(acc[i][2], acc[i][3]);
            ((__half2*)xh)[row * 32 + tx * 2]     = p0;
            ((__half2*)xh)[row * 32 + tx * 2 + 1] = p1;
            if (tx == 0) {
                as_[row] = ps;
                ad_[row] = pd;
            }
        }
    }
}

// Per-node lane-parallel softmax over in-edges (both heads): writes
// w1[e] = exp(a_e - m)/ (denom + eps) as float2 (head0, head1).
__global__ __launch_bounds__(256) void k_att1(
    const float* __restrict__ as_, const float* __restrict__ ad_,
    const int* __restrict__ offs, const int* __restrict__ csr,
    float2* __restrict__ w, int n) {
    int node = blockIdx.x * 4 + (threadIdx.x >> 6);
    if (node >= n) return;
    int l = threadIdx.x & 63;
    int beg = offs[node], end = offs[node + 1];
    float ad0 = ad_[node * 2 + 0];
    float ad1 = ad_[node * 2 + 1];

    float m0 = -1e30f, m1 = -1e30f, s0 = 0.f, s1 = 0.f;
    for (int base = beg; base < end; base += 64) {
        int idx = base + l;
        int si = (idx < end) ? csr[idx] : 0;
        float2 as2 = *(const float2*)&as_[si * 2];
        float a0 = as2.x + ad0; a0 = (a0 > 0.f) ? a0 : 0.2f * a0;
        float a1 = as2.y + ad1; a1 = (a1 > 0.f) ? a1 : 0.2f * a1;
        if (idx >= end) { a0 = -1e30f; a1 = -1e30f; }
        float cm0 = a0, cm1 = a1;
        for (int off = 1; off < 64; off <<= 1) {
            cm0 = fmaxf(cm0, __shfl_xor(cm0, off, 64));
            cm1 = fmaxf(cm1, __shfl_xor(cm1, off, 64));
        }
        float p0 = __expf(a0 - cm0);
        float p1 = __expf(a1 - cm1);
        for (int off = 1; off < 64; off <<= 1) {
            p0 += __shfl_xor(p0, off, 64);
            p1 += __shfl_xor(p1, off, 64);
        }
        float nm0 = fmaxf(m0, cm0);
        s0 = s0 * __expf(m0 - nm0) + p0 * __expf(cm0 - nm0);
        m0 = nm0;
        float nm1 = fmaxf(m1, cm1);
        s1 = s1 * __expf(m1 - nm1) + p1 * __expf(cm1 - nm1);
        m1 = nm1;
    }
    float inv0 = 1.0f / (s0 + 1e-16f);
    float inv1 = 1.0f / (s1 + 1e-16f);
    for (int base = beg; base < end; base += 64) {
        int idx = base + l;
        if (idx < end) {
            int si = csr[idx];
            float2 as2 = *(const float2*)&as_[si * 2];
            float a0 = as2.x + ad0; a0 = (a0 > 0.f) ? a0 : 0.2f * a0;
            float a1 = as2.y + ad1; a1 = (a1 > 0.f) ? a1 : 0.2f * a1;
            w[idx] = make_float2(__expf(a0 - m0) * inv0, __expf(a1 - m1) * inv1);
        }
    }
}

// Layer-2 softmax weights (1 head).
__global__ __launch_bounds__(256) void k_att2(
    const float* __restrict__ as_, const float* __restrict__ ad_,
    const int* __restrict__ offs, const int* __restrict__ csr,
    float* __restrict__ w, int n) {
    int node = blockIdx.x * 4 + (threadIdx.x >> 6);
    if (node >= n) return;
    int l = threadIdx.x & 63;
    int beg = offs[node], end = offs[node + 1];
    float ad = ad_[node];

    float m = -1e30f, s = 0.f;
    for (int base = beg; base < end; base += 64) {
        int idx = base + l;
        int si = (idx < end) ? csr[idx] : 0;
        float a = as_[si] + ad;
        a = (a > 0.f) ? a : 0.2f * a;
        if (idx >= end) a = -1e30f;
        float cm = a;
        for (int off = 1; off < 64; off <<= 1) cm = fmaxf(cm, __shfl_xor(cm, off, 64));
        float p = __expf(a - cm);
        for (int off = 1; off < 64; off <<= 1) p += __shfl_xor(p, off, 64);
        float nm = fmaxf(m, cm);
        s = s * __expf(m - nm) + p * __expf(cm - nm);
        m = nm;
    }
    float inv = 1.0f / (s + 1e-16f);
    for (int base = beg; base < end; base += 64) {
        int idx = base + l;
        if (idx < end) {
            int si = csr[idx];
            float a = as_[si] + ad;
            a = (a > 0.f) ? a : 0.2f * a;
            w[idx] = __expf(a - m) * inv;
        }
    }
}

// Weighted segment-sum of fp16 xh1 (lane owns channels 2l,2l+1; head=l>>5).
// 4 independent accumulator pairs for ILP.
__global__ __launch_bounds__(256) void k_agg1(
    const __half2* __restrict__ xh, const int* __restrict__ offs,
    const int* __restrict__ csr, const float2* __restrict__ w,
    const float* __restrict__ bias, float* __restrict__ hout, int n) {
    int node = blockIdx.x * 4 + (threadIdx.x >> 6);
    if (node >= n) return;
    int l = threadIdx.x & 63;
    int head = l >> 5;
    int beg = offs[node], end = offs[node + 1];

    float ax[4] = {0.f, 0.f, 0.f, 0.f};
    float ay[4] = {0.f, 0.f, 0.f, 0.f};
    int e = beg;
    for (; e + 4 <= end; e += 4) {
#pragma unroll
        for (int k = 0; k < 4; k++) {
            int si = csr[e + k];
            float2 wv = w[e + k];
            float wgt = head ? wv.y : wv.x;
            float2 xv = __half22float2(xh[si * 64 + l]);
            ax[k] += wgt * xv.x;
            ay[k] += wgt * xv.y;
        }
    }
    for (; e < end; e++) {
        int si = csr[e];
        float2 wv = w[e];
        float wgt = head ? wv.y : wv.x;
        float2 xv = __half22float2(xh[si * 64 + l]);
        ax[0] += wgt * xv.x;
        ay[0] += wgt * xv.y;
    }
    float a0 = (ax[0] + ax[1]) + (ax[2] + ax[3]);
    float a1 = (ay[0] + ay[1]) + (ay[2] + ay[3]);
    float2 bv = *(const float2*)&bias[2 * l];
    float o0 = fmaxf(a0 + bv.x, 0.f);
    float o1 = fmaxf(a1 + bv.y, 0.f);
    *(float2*)&hout[node * 128 + 2 * l] = make_float2(o0, o1);
}

// Weighted segment-sum of fp16 xh2 (lane owns channel l) + bias + L2 norm.
__global__ __launch_bounds__(256) void k_agg2(
    const __half* __restrict__ xh, const int* __restrict__ offs,
    const int* __restrict__ csr, const float* __restrict__ w,
    const float* __restrict__ bias, float* __restrict__ out, int n) {
    int node = blockIdx.x * 4 + (threadIdx.x >> 6);
    if (node >= n) return;
    int l = threadIdx.x & 63;
    int beg = offs[node], end = offs[node + 1];

    float acc[4] = {0.f, 0.f, 0.f, 0.f};
    int e = beg;
    for (; e + 4 <= end; e += 4) {
#pragma unroll
        for (int k = 0; k < 4; k++) {
            int si = csr[e + k];
            float wgt = w[e + k];
            acc[k] += wgt * __half2float(xh[si * 64 + l]);
        }
    }
    for (; e < end; e++) {
        int si = csr[e];
        acc[0] += w[e] * __half2float(xh[si * 64 + l]);
    }
    float o = (acc[0] + acc[1]) + (acc[2] + acc[3]) + bias[l];
    float sq = o * o;
    for (int off = 32; off; off >>= 1) sq += __shfl_xor(sq, off, 64);
    float nrm = sqrtf(sq);
    out[node * 64 + l] = o / fmaxf(nrm, 1e-12f);
}

extern "C" void kernel_launch(void* const* d_in, const int* in_sizes, int n_in,
                              void* d_out, int out_size, void* d_ws, size_t ws_size,
                              hipStream_t stream) {
    const float* x   = (const float*)d_in[0];
    const int*   ei  = (const int*)d_in[1];
    const float* W1  = (const float*)d_in[2];
    const float* as1 = (const float*)d_in[3];
    const float* ad1 = (const float*)d_in[4];
    const float* b1  = (const float*)d_in[5];
    const float* W2  = (const float*)d_in[6];
    const float* as2 = (const float*)d_in[7];
    const float* ad2 = (const float*)d_in[8];
    const float* b2  = (const float*)d_in[9];
    float* out = (float*)d_out;

    const int N  = in_sizes[0] / 128;
    const int E  = in_sizes[1] / 2;
    const int ET = E + N;

    char* ws = (char*)d_ws;
    size_t off = 0;
    auto alloc = [&](size_t bytes) -> char* {
        char* p = ws + off;
        off = (off + bytes + 255) & ~size_t(255);
        return p;
    };
    __half* xh1  = (__half*)alloc((size_t)N * 128 * 2);
    float*  hbuf = (float*)alloc((size_t)N * 128 * 4);
    __half* xh2  = (__half*)alloc((size_t)N * 64 * 2);
    float*  a_s1 = (float*)alloc((size_t)N * 2 * 4);
    float*  a_d1 = (float*)alloc((size_t)N * 2 * 4);
    float*  a_s2 = (float*)alloc((size_t)N * 4);
    float*  a_d2 = (float*)alloc((size_t)N * 4);
    float2* w1   = (float2*)alloc((size_t)ET * 8);
    float*  w2   = (float*)alloc((size_t)ET * 4);
    int*    deg  = (int*)alloc((size_t)N * 4);
    int*    offs = (int*)alloc((size_t)(N + 1) * 4);
    int*    curs = (int*)alloc((size_t)N * 4);
    int*    bsum = (int*)alloc(64 * 4);
    int*    csr  = (int*)alloc((size_t)ET * 4);

    hipMemsetAsync(deg, 0, (size_t)N * 4, stream);

    int gE = (ET + 255) / 256;
    k_hist<<<gE, 256, 0, stream>>>(ei + E, E, N, deg);

    int nb = (N + 1023) / 1024;
    k_scan1<<<nb, 1024, 0, stream>>>(deg, offs, bsum, N);
    k_scan2<<<1, 64, 0, stream>>>(bsum, nb);
    k_scan3<<<(N + 1 + 255) / 256, 256, 0, stream>>>(deg, offs, curs, bsum, N, ET);
    k_scatter<<<gE, 256, 0, stream>>>(ei, ei + E, E, N, curs, csr);

    int gN4 = (N + 3) / 4;
    k_gemm1<<<(N + 31) / 32, 256, 0, stream>>>(x, W1, as1, ad1, xh1, a_s1, a_d1, N);
    k_att1<<<gN4, 256, 0, stream>>>(a_s1, a_d1, offs, csr, w1, N);
    k_agg1<<<gN4, 256, 0, stream>>>((const __half2*)xh1, offs, csr, w1, b1, hbuf, N);
    k_gemm2<<<(N + 31) / 32, 256, 0, stream>>>(hbuf, W2, as2, ad2, xh2, a_s2, a_d2, N);
    k_att2<<<gN4, 256, 0, stream>>>(a_s2, a_d2, offs, csr, w2, N);
    k_agg2<<<gN4, 256, 0, stream>>>(xh2, offs, csr, w2, b2, out, N);
}

// Round 3
// 215.628 us; speedup vs baseline: 1.4666x; 1.3368x over previous
//
#include <hip/hip_runtime.h>
#include <hip/hip_fp16.h>

// ---------------------------------------------------------------------------
// 2-layer GAT on MI355X, round 3.
//   CSR build: hist (atomic rank) -> scan -> scatter (NO atomics)
//   k_gemm1: xh1 = x@W1^T (fp16 out) + attention dots
//   k_agg1 : fused softmax+aggregate, lane-parallel weights staged in LDS,
//            4-deep ILP gather-accumulate; h stored fp16
//   k_gemm2: xh2 = h(fp16)@W2^T (fp16 out) + attention dots
//   k_agg2 : fused softmax+aggregate + bias + row L2-normalize -> d_out fp32
// ---------------------------------------------------------------------------

__global__ void k_hist(const int* __restrict__ dst_e, int n_edges, int n_loops,
                       int* __restrict__ deg, int* __restrict__ rank) {
    int i = blockIdx.x * blockDim.x + threadIdx.x;
    int tot = n_edges + n_loops;
    if (i >= tot) return;
    int d = (i < n_edges) ? dst_e[i] : (i - n_edges);
    rank[i] = atomicAdd(&deg[d], 1);
}

__global__ void k_scan1(const int* __restrict__ deg, int* __restrict__ offs,
                        int* __restrict__ bsums, int n) {
    __shared__ int sm[1024];
    int tid = threadIdx.x;
    int i = blockIdx.x * 1024 + tid;
    int v = (i < n) ? deg[i] : 0;
    sm[tid] = v;
    __syncthreads();
    for (int off = 1; off < 1024; off <<= 1) {
        int t = (tid >= off) ? sm[tid - off] : 0;
        __syncthreads();
        sm[tid] += t;
        __syncthreads();
    }
    if (i < n) offs[i] = sm[tid];
    if (tid == 1023) bsums[blockIdx.x] = sm[1023];
}

__global__ void k_scan2(int* __restrict__ bsums, int nb) {
    int l = threadIdx.x;
    int v = (l < nb) ? bsums[l] : 0;
    int orig = v;
    for (int off = 1; off < 64; off <<= 1) {
        int u = __shfl_up(v, off, 64);
        if (l >= off) v += u;
    }
    if (l < nb) bsums[l] = v - orig;
}

__global__ void k_scan3(const int* __restrict__ deg, int* __restrict__ offs,
                        const int* __restrict__ bsums, int n, int total) {
    int i = blockIdx.x * blockDim.x + threadIdx.x;
    if (i < n) offs[i] = offs[i] - deg[i] + bsums[i >> 10];
    if (i == n) offs[n] = total;
}

// Pure scatter, no atomics: position = offs[dst] + rank (from k_hist).
__global__ void k_scatter(const int* __restrict__ src_e, const int* __restrict__ dst_e,
                          int n_edges, int n_loops, const int* __restrict__ offs,
                          const int* __restrict__ rank, int* __restrict__ csr_src) {
    int i = blockIdx.x * blockDim.x + threadIdx.x;
    int tot = n_edges + n_loops;
    if (i >= tot) return;
    int s = (i < n_edges) ? src_e[i] : (i - n_edges);
    int d = (i < n_edges) ? dst_e[i] : (i - n_edges);
    csr_src[offs[d] + rank[i]] = s;
}

// xh1 = x @ W1^T (N x 128 @ 128 x 128) -> fp16; fused attention dots (fp32).
__global__ __launch_bounds__(256) void k_gemm1(
    const float* __restrict__ x, const float* __restrict__ W,
    const float* __restrict__ att_s, const float* __restrict__ att_d,
    __half* __restrict__ xh, float* __restrict__ as_, float* __restrict__ ad_,
    int n) {
    __shared__ float xs[32][128];
    __shared__ float wt[32][132];
    int t = threadIdx.x;
    int tx = t & 31;
    int ty = t >> 5;
    int row0 = blockIdx.x * 32;

    for (int i = 0; i < 16; i++) {
        int flat = i * 256 + t;
        int r = flat >> 7, k = flat & 127;
        int rr = row0 + r;
        xs[r][k] = (rr < n) ? x[rr * 128 + k] : 0.0f;
    }

    float acc[4][4];
#pragma unroll
    for (int i = 0; i < 4; i++)
#pragma unroll
        for (int j = 0; j < 4; j++) acc[i][j] = 0.f;

    for (int kb = 0; kb < 4; kb++) {
        __syncthreads();
        for (int i = 0; i < 16; i++) {
            int flat = i * 256 + t;
            int kk = flat & 31, c = flat >> 5;
            wt[kk][c] = W[c * 128 + kb * 32 + kk];
        }
        __syncthreads();
#pragma unroll 8
        for (int kk = 0; kk < 32; kk++) {
            float4 w = *(const float4*)&wt[kk][tx * 4];
#pragma unroll
            for (int i = 0; i < 4; i++) {
                float xv = xs[ty + 8 * i][kb * 32 + kk];
                acc[i][0] += xv * w.x;
                acc[i][1] += xv * w.y;
                acc[i][2] += xv * w.z;
                acc[i][3] += xv * w.w;
            }
        }
    }

    float asv[4], adv[4];
#pragma unroll
    for (int j = 0; j < 4; j++) {
        asv[j] = att_s[tx * 4 + j];
        adv[j] = att_d[tx * 4 + j];
    }
#pragma unroll
    for (int i = 0; i < 4; i++) {
        int row = row0 + ty + 8 * i;
        float ps = 0.f, pd = 0.f;
#pragma unroll
        for (int j = 0; j < 4; j++) {
            ps += acc[i][j] * asv[j];
            pd += acc[i][j] * adv[j];
        }
        for (int off = 1; off < 16; off <<= 1) {
            ps += __shfl_xor(ps, off, 64);
            pd += __shfl_xor(pd, off, 64);
        }
        if (row < n) {
            __half2 p0 = __floats2half2_rn(acc[i][0], acc[i][1]);
            __half2 p1 = __floats2half2_rn(acc[i][2], acc[i][3]);
            ((__half2*)xh)[row * 64 + tx * 2]     = p0;
            ((__half2*)xh)[row * 64 + tx * 2 + 1] = p1;
            if ((tx & 15) == 0) {
                int head = tx >> 4;
                as_[row * 2 + head] = ps;
                ad_[row * 2 + head] = pd;
            }
        }
    }
}

// xh2 = h(fp16) @ W2^T (N x 128 @ 128 x 64) -> fp16; fused attention dots.
__global__ __launch_bounds__(256) void k_gemm2(
    const __half* __restrict__ h, const float* __restrict__ W,
    const float* __restrict__ att_s, const float* __restrict__ att_d,
    __half* __restrict__ xh, float* __restrict__ as_, float* __restrict__ ad_,
    int n) {
    __shared__ float xs[32][128];
    __shared__ float wt[32][68];
    int t = threadIdx.x;
    int tx = t & 15;
    int ty = t >> 4;
    int row0 = blockIdx.x * 32;

    for (int i = 0; i < 8; i++) {   // 32 rows x 64 half2
        int flat = i * 256 + t;
        int r = flat >> 6, k2 = flat & 63;
        int rr = row0 + r;
        __half2 hv = (rr < n) ? ((const __half2*)h)[rr * 64 + k2]
                              : __floats2half2_rn(0.f, 0.f);
        float2 f = __half22float2(hv);
        xs[r][2 * k2]     = f.x;
        xs[r][2 * k2 + 1] = f.y;
    }

    float acc[2][4];
#pragma unroll
    for (int i = 0; i < 2; i++)
#pragma unroll
        for (int j = 0; j < 4; j++) acc[i][j] = 0.f;

    for (int kb = 0; kb < 4; kb++) {
        __syncthreads();
        for (int i = 0; i < 8; i++) {
            int flat = i * 256 + t;
            int kk = flat & 31, c = flat >> 5;
            wt[kk][c] = W[c * 128 + kb * 32 + kk];
        }
        __syncthreads();
#pragma unroll 8
        for (int kk = 0; kk < 32; kk++) {
            float4 w = *(const float4*)&wt[kk][tx * 4];
#pragma unroll
            for (int i = 0; i < 2; i++) {
                float xv = xs[ty + 16 * i][kb * 32 + kk];
                acc[i][0] += xv * w.x;
                acc[i][1] += xv * w.y;
                acc[i][2] += xv * w.z;
                acc[i][3] += xv * w.w;
            }
        }
    }

    float asv[4], adv[4];
#pragma unroll
    for (int j = 0; j < 4; j++) {
        asv[j] = att_s[tx * 4 + j];
        adv[j] = att_d[tx * 4 + j];
    }
#pragma unroll
    for (int i = 0; i < 2; i++) {
        int row = row0 + ty + 16 * i;
        float ps = 0.f, pd = 0.f;
#pragma unroll
        for (int j = 0; j < 4; j++) {
            ps += acc[i][j] * asv[j];
            pd += acc[i][j] * adv[j];
        }
        for (int off = 1; off < 16; off <<= 1) {
            ps += __shfl_xor(ps, off, 64);
            pd += __shfl_xor(pd, off, 64);
        }
        if (row < n) {
            __half2 p0 = __floats2half2_rn(acc[i][0], acc[i][1]);
            __half2 p1 = __floats2half2_rn(acc[i][2], acc[i][3]);
            ((__half2*)xh)[row * 32 + tx * 2]     = p0;
            ((__half2*)xh)[row * 32 + tx * 2 + 1] = p1;
            if (tx == 0) {
                as_[row] = ps;
                ad_[row] = pd;
            }
        }
    }
}

// Fused softmax + aggregate, layer 1. One wave per node; lane owns channels
// 2l,2l+1 (head = l>>5). Pass 1: lane-parallel softmax stats. Pass 2: weights
// computed lane-parallel, staged in LDS, consumed by 4-deep ILP gather loop.
__global__ __launch_bounds__(256) void k_agg1(
    const __half2* __restrict__ xh, const float* __restrict__ as_,
    const float* __restrict__ ad_, const int* __restrict__ offs,
    const int* __restrict__ csr, const float* __restrict__ bias,
    __half2* __restrict__ hout, int n) {
    __shared__ float wsm[4][2][64];
    __shared__ int   ssm[4][64];
    int wid = threadIdx.x >> 6;
    int l = threadIdx.x & 63;
    int node = blockIdx.x * 4 + wid;
    if (node >= n) return;
    int head = l >> 5;
    int beg = offs[node], end = offs[node + 1];
    float ad0 = ad_[node * 2 + 0];
    float ad1 = ad_[node * 2 + 1];

    // pass 1: softmax max + denom (lane-parallel across edges)
    float m0 = -1e30f, m1 = -1e30f, s0 = 0.f, s1 = 0.f;
    for (int base = beg; base < end; base += 64) {
        int idx = base + l;
        int si = (idx < end) ? csr[idx] : 0;
        float2 as2 = *(const float2*)&as_[si * 2];
        float a0 = as2.x + ad0; a0 = (a0 > 0.f) ? a0 : 0.2f * a0;
        float a1 = as2.y + ad1; a1 = (a1 > 0.f) ? a1 : 0.2f * a1;
        if (idx >= end) { a0 = -1e30f; a1 = -1e30f; }
        float cm0 = a0, cm1 = a1;
        for (int off = 1; off < 64; off <<= 1) {
            cm0 = fmaxf(cm0, __shfl_xor(cm0, off, 64));
            cm1 = fmaxf(cm1, __shfl_xor(cm1, off, 64));
        }
        float p0 = __expf(a0 - cm0);
        float p1 = __expf(a1 - cm1);
        for (int off = 1; off < 64; off <<= 1) {
            p0 += __shfl_xor(p0, off, 64);
            p1 += __shfl_xor(p1, off, 64);
        }
        float nm0 = fmaxf(m0, cm0);
        s0 = s0 * __expf(m0 - nm0) + p0 * __expf(cm0 - nm0);
        m0 = nm0;
        float nm1 = fmaxf(m1, cm1);
        s1 = s1 * __expf(m1 - nm1) + p1 * __expf(cm1 - nm1);
        m1 = nm1;
    }
    float inv0 = 1.0f / (s0 + 1e-16f);
    float inv1 = 1.0f / (s1 + 1e-16f);

    // pass 2: weights lane-parallel -> LDS; serial 4-deep gather-accumulate
    float ax[4] = {0.f, 0.f, 0.f, 0.f};
    float ay[4] = {0.f, 0.f, 0.f, 0.f};
    for (int base = beg; base < end; base += 64) {
        int idx = base + l;
        int si = (idx < end) ? csr[idx] : 0;
        float2 as2 = *(const float2*)&as_[si * 2];
        float a0 = as2.x + ad0; a0 = (a0 > 0.f) ? a0 : 0.2f * a0;
        float a1 = as2.y + ad1; a1 = (a1 > 0.f) ? a1 : 0.2f * a1;
        wsm[wid][0][l] = __expf(a0 - m0) * inv0;
        wsm[wid][1][l] = __expf(a1 - m1) * inv1;
        ssm[wid][l] = si;
        int cnt = min(64, end - base);
        int k = 0;
        for (; k + 4 <= cnt; k += 4) {
#pragma unroll
            for (int u = 0; u < 4; u++) {
                int j = k + u;
                int sj = ssm[wid][j];
                float wgt = wsm[wid][head][j];
                float2 xv = __half22float2(xh[sj * 64 + l]);
                ax[u] += wgt * xv.x;
                ay[u] += wgt * xv.y;
            }
        }
        for (; k < cnt; k++) {
            int sj = ssm[wid][k];
            float wgt = wsm[wid][head][k];
            float2 xv = __half22float2(xh[sj * 64 + l]);
            ax[0] += wgt * xv.x;
            ay[0] += wgt * xv.y;
        }
    }
    float a0 = (ax[0] + ax[1]) + (ax[2] + ax[3]);
    float a1 = (ay[0] + ay[1]) + (ay[2] + ay[3]);
    float2 bv = *(const float2*)&bias[2 * l];
    float o0 = fmaxf(a0 + bv.x, 0.f);
    float o1 = fmaxf(a1 + bv.y, 0.f);
    hout[node * 64 + l] = __floats2half2_rn(o0, o1);
}

// Fused softmax + aggregate + bias + L2-normalize, layer 2 (1 head).
__global__ __launch_bounds__(256) void k_agg2(
    const __half* __restrict__ xh, const float* __restrict__ as_,
    const float* __restrict__ ad_, const int* __restrict__ offs,
    const int* __restrict__ csr, const float* __restrict__ bias,
    float* __restrict__ out, int n) {
    __shared__ float wsm[4][64];
    __shared__ int   ssm[4][64];
    int wid = threadIdx.x >> 6;
    int l = threadIdx.x & 63;
    int node = blockIdx.x * 4 + wid;
    if (node >= n) return;
    int beg = offs[node], end = offs[node + 1];
    float ad = ad_[node];

    float m = -1e30f, s = 0.f;
    for (int base = beg; base < end; base += 64) {
        int idx = base + l;
        int si = (idx < end) ? csr[idx] : 0;
        float a = as_[si] + ad;
        a = (a > 0.f) ? a : 0.2f * a;
        if (idx >= end) a = -1e30f;
        float cm = a;
        for (int off = 1; off < 64; off <<= 1) cm = fmaxf(cm, __shfl_xor(cm, off, 64));
        float p = __expf(a - cm);
        for (int off = 1; off < 64; off <<= 1) p += __shfl_xor(p, off, 64);
        float nm = fmaxf(m, cm);
        s = s * __expf(m - nm) + p * __expf(cm - nm);
        m = nm;
    }
    float inv = 1.0f / (s + 1e-16f);

    float acc[4] = {0.f, 0.f, 0.f, 0.f};
    for (int base = beg; base < end; base += 64) {
        int idx = base + l;
        int si = (idx < end) ? csr[idx] : 0;
        float a = as_[si] + ad;
        a = (a > 0.f) ? a : 0.2f * a;
        wsm[wid][l] = __expf(a - m) * inv;
        ssm[wid][l] = si;
        int cnt = min(64, end - base);
        int k = 0;
        for (; k + 4 <= cnt; k += 4) {
#pragma unroll
            for (int u = 0; u < 4; u++) {
                int j = k + u;
                int sj = ssm[wid][j];
                acc[u] += wsm[wid][j] * __half2float(xh[sj * 64 + l]);
            }
        }
        for (; k < cnt; k++) {
            int sj = ssm[wid][k];
            acc[0] += wsm[wid][k] * __half2float(xh[sj * 64 + l]);
        }
    }
    float o = (acc[0] + acc[1]) + (acc[2] + acc[3]) + bias[l];
    float sq = o * o;
    for (int off = 32; off; off >>= 1) sq += __shfl_xor(sq, off, 64);
    float nrm = sqrtf(sq);
    out[node * 64 + l] = o / fmaxf(nrm, 1e-12f);
}

extern "C" void kernel_launch(void* const* d_in, const int* in_sizes, int n_in,
                              void* d_out, int out_size, void* d_ws, size_t ws_size,
                              hipStream_t stream) {
    const float* x   = (const float*)d_in[0];
    const int*   ei  = (const int*)d_in[1];
    const float* W1  = (const float*)d_in[2];
    const float* as1 = (const float*)d_in[3];
    const float* ad1 = (const float*)d_in[4];
    const float* b1  = (const float*)d_in[5];
    const float* W2  = (const float*)d_in[6];
    const float* as2 = (const float*)d_in[7];
    const float* ad2 = (const float*)d_in[8];
    const float* b2  = (const float*)d_in[9];
    float* out = (float*)d_out;

    const int N  = in_sizes[0] / 128;
    const int E  = in_sizes[1] / 2;
    const int ET = E + N;

    char* ws = (char*)d_ws;
    size_t off = 0;
    auto alloc = [&](size_t bytes) -> char* {
        char* p = ws + off;
        off = (off + bytes + 255) & ~size_t(255);
        return p;
    };
    __half* xh1  = (__half*)alloc((size_t)N * 128 * 2);
    __half* hbuf = (__half*)alloc((size_t)N * 128 * 2);
    __half* xh2  = (__half*)alloc((size_t)N * 64 * 2);
    float*  a_s1 = (float*)alloc((size_t)N * 2 * 4);
    float*  a_d1 = (float*)alloc((size_t)N * 2 * 4);
    float*  a_s2 = (float*)alloc((size_t)N * 4);
    float*  a_d2 = (float*)alloc((size_t)N * 4);
    int*    deg  = (int*)alloc((size_t)N * 4);
    int*    offs = (int*)alloc((size_t)(N + 1) * 4);
    int*    rank = (int*)alloc((size_t)ET * 4);
    int*    bsum = (int*)alloc(64 * 4);
    int*    csr  = (int*)alloc((size_t)ET * 4);

    hipMemsetAsync(deg, 0, (size_t)N * 4, stream);

    int gE = (ET + 255) / 256;
    k_hist<<<gE, 256, 0, stream>>>(ei + E, E, N, deg, rank);

    int nb = (N + 1023) / 1024;
    k_scan1<<<nb, 1024, 0, stream>>>(deg, offs, bsum, N);
    k_scan2<<<1, 64, 0, stream>>>(bsum, nb);
    k_scan3<<<(N + 1 + 255) / 256, 256, 0, stream>>>(deg, offs, bsum, N, ET);
    k_scatter<<<gE, 256, 0, stream>>>(ei, ei + E, E, N, offs, rank, csr);

    int gN4 = (N + 3) / 4;
    k_gemm1<<<(N + 31) / 32, 256, 0, stream>>>(x, W1, as1, ad1, xh1, a_s1, a_d1, N);
    k_agg1<<<gN4, 256, 0, stream>>>((const __half2*)xh1, a_s1, a_d1, offs, csr, b1,
                                    (__half2*)hbuf, N);
    k_gemm2<<<(N + 31) / 32, 256, 0, stream>>>(hbuf, W2, as2, ad2, xh2, a_s2, a_d2, N);
    k_agg2<<<gN4, 256, 0, stream>>>(xh2, a_s2, a_d2, offs, csr, b2, out, N);
}

// Round 4
// 171.309 us; speedup vs baseline: 1.8460x; 1.2587x over previous
//
#include <hip/hip_runtime.h>
#include <hip/hip_fp16.h>

// ---------------------------------------------------------------------------
// 2-layer GAT on MI355X, round 4.
//   CSR build: hist (atomic rank) -> scan -> scatter (NO atomics)
//   k_gemm1: MFMA fp16  xh1 = x@W1^T + attention dots  (swapped-operand epilogue)
//   k_agg1 : fused softmax+aggregate (LDS-staged weights), h stored fp16
//   k_gemm2: MFMA fp16  xh2 = h@W2^T + attention dots
//   k_agg2 : fused softmax+aggregate + bias + row L2-normalize -> d_out fp32
// ---------------------------------------------------------------------------

typedef _Float16 half8  __attribute__((ext_vector_type(8)));
typedef _Float16 half4v __attribute__((ext_vector_type(4)));
typedef float    f32x4  __attribute__((ext_vector_type(4)));

__global__ void k_hist(const int* __restrict__ dst_e, int n_edges, int n_loops,
                       int* __restrict__ deg, int* __restrict__ rank) {
    int i = blockIdx.x * blockDim.x + threadIdx.x;
    int tot = n_edges + n_loops;
    if (i >= tot) return;
    int d = (i < n_edges) ? dst_e[i] : (i - n_edges);
    rank[i] = atomicAdd(&deg[d], 1);
}

__global__ void k_scan1(const int* __restrict__ deg, int* __restrict__ offs,
                        int* __restrict__ bsums, int n) {
    __shared__ int sm[1024];
    int tid = threadIdx.x;
    int i = blockIdx.x * 1024 + tid;
    int v = (i < n) ? deg[i] : 0;
    sm[tid] = v;
    __syncthreads();
    for (int off = 1; off < 1024; off <<= 1) {
        int t = (tid >= off) ? sm[tid - off] : 0;
        __syncthreads();
        sm[tid] += t;
        __syncthreads();
    }
    if (i < n) offs[i] = sm[tid];
    if (tid == 1023) bsums[blockIdx.x] = sm[1023];
}

__global__ void k_scan2(int* __restrict__ bsums, int nb) {
    int l = threadIdx.x;
    int v = (l < nb) ? bsums[l] : 0;
    int orig = v;
    for (int off = 1; off < 64; off <<= 1) {
        int u = __shfl_up(v, off, 64);
        if (l >= off) v += u;
    }
    if (l < nb) bsums[l] = v - orig;
}

__global__ void k_scan3(const int* __restrict__ deg, int* __restrict__ offs,
                        const int* __restrict__ bsums, int n, int total) {
    int i = blockIdx.x * blockDim.x + threadIdx.x;
    if (i < n) offs[i] = offs[i] - deg[i] + bsums[i >> 10];
    if (i == n) offs[n] = total;
}

__global__ void k_scatter(const int* __restrict__ src_e, const int* __restrict__ dst_e,
                          int n_edges, int n_loops, const int* __restrict__ offs,
                          const int* __restrict__ rank, int* __restrict__ csr_src) {
    int i = blockIdx.x * blockDim.x + threadIdx.x;
    int tot = n_edges + n_loops;
    if (i >= tot) return;
    int s = (i < n_edges) ? src_e[i] : (i - n_edges);
    int d = (i < n_edges) ? dst_e[i] : (i - n_edges);
    csr_src[offs[d] + rank[i]] = s;
}

// MFMA GEMM1: xh1[r][c] = sum_k x[r][k] * W[c][k], 64 rows/block, 128 cols.
// A-operand = W rows (output cols), B-operand = x rows => lane holds one output
// row (lane&15) and 4 consecutive cols per tile: contiguous half4 stores.
__global__ __launch_bounds__(256) void k_gemm1(
    const float* __restrict__ x, const float* __restrict__ W,
    const float* __restrict__ att_s, const float* __restrict__ att_d,
    _Float16* __restrict__ xh, float* __restrict__ as_, float* __restrict__ ad_,
    int n) {
    __shared__ __align__(16) char lds[49152];
    char* xs = lds;            // 64 rows * 256B (fp16, swizzled)
    char* ws = lds + 16384;    // 128 rows * 256B
    int t = threadIdx.x;
    int row0 = blockIdx.x * 64;

    // stage x tile (fp32 -> fp16), swizzle byte ^= (row&7)<<4
#pragma unroll
    for (int i = 0; i < 8; i++) {
        int flat = i * 256 + t;
        int r = flat >> 5, k4 = flat & 31;
        int rr = row0 + r;
        float4 v = make_float4(0.f, 0.f, 0.f, 0.f);
        if (rr < n) v = ((const float4*)x)[rr * 32 + k4];
        half4v hv;
        hv[0] = (_Float16)v.x; hv[1] = (_Float16)v.y;
        hv[2] = (_Float16)v.z; hv[3] = (_Float16)v.w;
        int byte = (r * 256 + k4 * 8) ^ ((r & 7) << 4);
        *(half4v*)(xs + byte) = hv;
    }
    // stage whole W (128x128 fp32 -> fp16)
#pragma unroll
    for (int i = 0; i < 16; i++) {
        int flat = i * 256 + t;
        int c = flat >> 5, k4 = flat & 31;
        float4 v = ((const float4*)W)[c * 32 + k4];
        half4v hv;
        hv[0] = (_Float16)v.x; hv[1] = (_Float16)v.y;
        hv[2] = (_Float16)v.z; hv[3] = (_Float16)v.w;
        int byte = (c * 256 + k4 * 8) ^ ((c & 7) << 4);
        *(half4v*)(ws + byte) = hv;
    }
    __syncthreads();

    int l = t & 63, wv = t >> 6;
    int r16 = l & 15, g = l >> 4;

    f32x4 acc[8];
#pragma unroll
    for (int mt = 0; mt < 8; mt++) acc[mt] = (f32x4){0.f, 0.f, 0.f, 0.f};

    int xrow = wv * 16 + r16;
#pragma unroll
    for (int ks = 0; ks < 4; ks++) {
        int xbyte = (xrow * 256 + ks * 64 + g * 16) ^ ((xrow & 7) << 4);
        half8 bfrag = *(const half8*)(xs + xbyte);
#pragma unroll
        for (int mt = 0; mt < 8; mt++) {
            int wrow = mt * 16 + r16;
            int wbyte = (wrow * 256 + ks * 64 + g * 16) ^ ((wrow & 7) << 4);
            half8 afrag = *(const half8*)(ws + wbyte);
            acc[mt] = __builtin_amdgcn_mfma_f32_16x16x32_f16(afrag, bfrag, acc[mt], 0, 0, 0);
        }
    }

    int row = row0 + xrow;
    float ps0 = 0.f, ps1 = 0.f, pd0 = 0.f, pd1 = 0.f;
#pragma unroll
    for (int mt = 0; mt < 8; mt++) {
#pragma unroll
        for (int j = 0; j < 4; j++) {
            int col = mt * 16 + g * 4 + j;
            float v = acc[mt][j];
            float av = att_s[col], dv = att_d[col];
            if (mt < 4) { ps0 += v * av; pd0 += v * dv; }
            else        { ps1 += v * av; pd1 += v * dv; }
        }
    }
    ps0 += __shfl_xor(ps0, 16, 64); ps0 += __shfl_xor(ps0, 32, 64);
    ps1 += __shfl_xor(ps1, 16, 64); ps1 += __shfl_xor(ps1, 32, 64);
    pd0 += __shfl_xor(pd0, 16, 64); pd0 += __shfl_xor(pd0, 32, 64);
    pd1 += __shfl_xor(pd1, 16, 64); pd1 += __shfl_xor(pd1, 32, 64);

    if (row < n) {
#pragma unroll
        for (int mt = 0; mt < 8; mt++) {
            half4v o;
            o[0] = (_Float16)acc[mt][0]; o[1] = (_Float16)acc[mt][1];
            o[2] = (_Float16)acc[mt][2]; o[3] = (_Float16)acc[mt][3];
            *(half4v*)(xh + row * 128 + mt * 16 + g * 4) = o;
        }
        if (g == 0) {
            ((float2*)as_)[row] = make_float2(ps0, ps1);
            ((float2*)ad_)[row] = make_float2(pd0, pd1);
        }
    }
}

// MFMA GEMM2: xh2 = h(fp16) @ W2^T (64 cols), single head.
__global__ __launch_bounds__(256) void k_gemm2(
    const _Float16* __restrict__ h, const float* __restrict__ W,
    const float* __restrict__ att_s, const float* __restrict__ att_d,
    _Float16* __restrict__ xh, float* __restrict__ as_, float* __restrict__ ad_,
    int n) {
    __shared__ __align__(16) char lds[32768];
    char* xs = lds;            // 64 rows * 256B
    char* ws = lds + 16384;    // 64 rows * 256B
    int t = threadIdx.x;
    int row0 = blockIdx.x * 64;

#pragma unroll
    for (int i = 0; i < 4; i++) {   // h tile: 64 rows x 16 chunks of 16B
        int flat = i * 256 + t;
        int r = flat >> 4, kc = flat & 15;
        int rr = row0 + r;
        half8 hv = (half8)(_Float16)0.f;
        if (rr < n) hv = *(const half8*)(h + rr * 128 + kc * 8);
        int byte = (r * 256 + kc * 16) ^ ((r & 7) << 4);
        *(half8*)(xs + byte) = hv;
    }
#pragma unroll
    for (int i = 0; i < 8; i++) {   // W2: 64 rows x 32 float4
        int flat = i * 256 + t;
        int c = flat >> 5, k4 = flat & 31;
        float4 v = ((const float4*)W)[c * 32 + k4];
        half4v hv;
        hv[0] = (_Float16)v.x; hv[1] = (_Float16)v.y;
        hv[2] = (_Float16)v.z; hv[3] = (_Float16)v.w;
        int byte = (c * 256 + k4 * 8) ^ ((c & 7) << 4);
        *(half4v*)(ws + byte) = hv;
    }
    __syncthreads();

    int l = t & 63, wv = t >> 6;
    int r16 = l & 15, g = l >> 4;

    f32x4 acc[4];
#pragma unroll
    for (int mt = 0; mt < 4; mt++) acc[mt] = (f32x4){0.f, 0.f, 0.f, 0.f};

    int xrow = wv * 16 + r16;
#pragma unroll
    for (int ks = 0; ks < 4; ks++) {
        int xbyte = (xrow * 256 + ks * 64 + g * 16) ^ ((xrow & 7) << 4);
        half8 bfrag = *(const half8*)(xs + xbyte);
#pragma unroll
        for (int mt = 0; mt < 4; mt++) {
            int wrow = mt * 16 + r16;
            int wbyte = (wrow * 256 + ks * 64 + g * 16) ^ ((wrow & 7) << 4);
            half8 afrag = *(const half8*)(ws + wbyte);
            acc[mt] = __builtin_amdgcn_mfma_f32_16x16x32_f16(afrag, bfrag, acc[mt], 0, 0, 0);
        }
    }

    int row = row0 + xrow;
    float ps = 0.f, pd = 0.f;
#pragma unroll
    for (int mt = 0; mt < 4; mt++) {
#pragma unroll
        for (int j = 0; j < 4; j++) {
            int col = mt * 16 + g * 4 + j;
            float v = acc[mt][j];
            ps += v * att_s[col];
            pd += v * att_d[col];
        }
    }
    ps += __shfl_xor(ps, 16, 64); ps += __shfl_xor(ps, 32, 64);
    pd += __shfl_xor(pd, 16, 64); pd += __shfl_xor(pd, 32, 64);

    if (row < n) {
#pragma unroll
        for (int mt = 0; mt < 4; mt++) {
            half4v o;
            o[0] = (_Float16)acc[mt][0]; o[1] = (_Float16)acc[mt][1];
            o[2] = (_Float16)acc[mt][2]; o[3] = (_Float16)acc[mt][3];
            *(half4v*)(xh + row * 64 + mt * 16 + g * 4) = o;
        }
        if (g == 0) { as_[row] = ps; ad_[row] = pd; }
    }
}

// Fused softmax + aggregate, layer 1 (2 heads). One wave/node, lane owns
// channels 2l,2l+1 (head=l>>5).
__global__ __launch_bounds__(256) void k_agg1(
    const __half2* __restrict__ xh, const float* __restrict__ as_,
    const float* __restrict__ ad_, const int* __restrict__ offs,
    const int* __restrict__ csr, const float* __restrict__ bias,
    __half2* __restrict__ hout, int n) {
    __shared__ float wsm[4][2][64];
    __shared__ int   ssm[4][64];
    int wid = threadIdx.x >> 6;
    int l = threadIdx.x & 63;
    int node = blockIdx.x * 4 + wid;
    if (node >= n) return;
    int head = l >> 5;
    int beg = offs[node], end = offs[node + 1];
    float ad0 = ad_[node * 2 + 0];
    float ad1 = ad_[node * 2 + 1];

    float m0 = -1e30f, m1 = -1e30f, s0 = 0.f, s1 = 0.f;
    for (int base = beg; base < end; base += 64) {
        int idx = base + l;
        int si = (idx < end) ? csr[idx] : 0;
        float2 as2 = *(const float2*)&as_[si * 2];
        float a0 = as2.x + ad0; a0 = (a0 > 0.f) ? a0 : 0.2f * a0;
        float a1 = as2.y + ad1; a1 = (a1 > 0.f) ? a1 : 0.2f * a1;
        if (idx >= end) { a0 = -1e30f; a1 = -1e30f; }
        float cm0 = a0, cm1 = a1;
        for (int off = 1; off < 64; off <<= 1) {
            cm0 = fmaxf(cm0, __shfl_xor(cm0, off, 64));
            cm1 = fmaxf(cm1, __shfl_xor(cm1, off, 64));
        }
        float p0 = __expf(a0 - cm0);
        float p1 = __expf(a1 - cm1);
        for (int off = 1; off < 64; off <<= 1) {
            p0 += __shfl_xor(p0, off, 64);
            p1 += __shfl_xor(p1, off, 64);
        }
        float nm0 = fmaxf(m0, cm0);
        s0 = s0 * __expf(m0 - nm0) + p0 * __expf(cm0 - nm0);
        m0 = nm0;
        float nm1 = fmaxf(m1, cm1);
        s1 = s1 * __expf(m1 - nm1) + p1 * __expf(cm1 - nm1);
        m1 = nm1;
    }
    float inv0 = 1.0f / (s0 + 1e-16f);
    float inv1 = 1.0f / (s1 + 1e-16f);

    float ax[4] = {0.f, 0.f, 0.f, 0.f};
    float ay[4] = {0.f, 0.f, 0.f, 0.f};
    for (int base = beg; base < end; base += 64) {
        int idx = base + l;
        int si = (idx < end) ? csr[idx] : 0;
        float2 as2 = *(const float2*)&as_[si * 2];
        float a0 = as2.x + ad0; a0 = (a0 > 0.f) ? a0 : 0.2f * a0;
        float a1 = as2.y + ad1; a1 = (a1 > 0.f) ? a1 : 0.2f * a1;
        wsm[wid][0][l] = __expf(a0 - m0) * inv0;
        wsm[wid][1][l] = __expf(a1 - m1) * inv1;
        ssm[wid][l] = si;
        int cnt = min(64, end - base);
        int k = 0;
        for (; k + 4 <= cnt; k += 4) {
#pragma unroll
            for (int u = 0; u < 4; u++) {
                int j = k + u;
                int sj = ssm[wid][j];
                float wgt = wsm[wid][head][j];
                float2 xv = __half22float2(xh[sj * 64 + l]);
                ax[u] += wgt * xv.x;
                ay[u] += wgt * xv.y;
            }
        }
        for (; k < cnt; k++) {
            int sj = ssm[wid][k];
            float wgt = wsm[wid][head][k];
            float2 xv = __half22float2(xh[sj * 64 + l]);
            ax[0] += wgt * xv.x;
            ay[0] += wgt * xv.y;
        }
    }
    float a0 = (ax[0] + ax[1]) + (ax[2] + ax[3]);
    float a1 = (ay[0] + ay[1]) + (ay[2] + ay[3]);
    float2 bv = *(const float2*)&bias[2 * l];
    float o0 = fmaxf(a0 + bv.x, 0.f);
    float o1 = fmaxf(a1 + bv.y, 0.f);
    hout[node * 64 + l] = __floats2half2_rn(o0, o1);
}

// Fused softmax + aggregate + bias + L2-normalize, layer 2 (1 head).
__global__ __launch_bounds__(256) void k_agg2(
    const __half* __restrict__ xh, const float* __restrict__ as_,
    const float* __restrict__ ad_, const int* __restrict__ offs,
    const int* __restrict__ csr, const float* __restrict__ bias,
    float* __restrict__ out, int n) {
    __shared__ float wsm[4][64];
    __shared__ int   ssm[4][64];
    int wid = threadIdx.x >> 6;
    int l = threadIdx.x & 63;
    int node = blockIdx.x * 4 + wid;
    if (node >= n) return;
    int beg = offs[node], end = offs[node + 1];
    float ad = ad_[node];

    float m = -1e30f, s = 0.f;
    for (int base = beg; base < end; base += 64) {
        int idx = base + l;
        int si = (idx < end) ? csr[idx] : 0;
        float a = as_[si] + ad;
        a = (a > 0.f) ? a : 0.2f * a;
        if (idx >= end) a = -1e30f;
        float cm = a;
        for (int off = 1; off < 64; off <<= 1) cm = fmaxf(cm, __shfl_xor(cm, off, 64));
        float p = __expf(a - cm);
        for (int off = 1; off < 64; off <<= 1) p += __shfl_xor(p, off, 64);
        float nm = fmaxf(m, cm);
        s = s * __expf(m - nm) + p * __expf(cm - nm);
        m = nm;
    }
    float inv = 1.0f / (s + 1e-16f);

    float acc[4] = {0.f, 0.f, 0.f, 0.f};
    for (int base = beg; base < end; base += 64) {
        int idx = base + l;
        int si = (idx < end) ? csr[idx] : 0;
        float a = as_[si] + ad;
        a = (a > 0.f) ? a : 0.2f * a;
        wsm[wid][l] = __expf(a - m) * inv;
        ssm[wid][l] = si;
        int cnt = min(64, end - base);
        int k = 0;
        for (; k + 4 <= cnt; k += 4) {
#pragma unroll
            for (int u = 0; u < 4; u++) {
                int j = k + u;
                int sj = ssm[wid][j];
                acc[u] += wsm[wid][j] * __half2float(((const __half*)xh)[sj * 64 + l]);
            }
        }
        for (; k < cnt; k++) {
            int sj = ssm[wid][k];
            acc[0] += wsm[wid][k] * __half2float(((const __half*)xh)[sj * 64 + l]);
        }
    }
    float o = (acc[0] + acc[1]) + (acc[2] + acc[3]) + bias[l];
    float sq = o * o;
    for (int off = 32; off; off >>= 1) sq += __shfl_xor(sq, off, 64);
    float nrm = sqrtf(sq);
    out[node * 64 + l] = o / fmaxf(nrm, 1e-12f);
}

extern "C" void kernel_launch(void* const* d_in, const int* in_sizes, int n_in,
                              void* d_out, int out_size, void* d_ws, size_t ws_size,
                              hipStream_t stream) {
    const float* x   = (const float*)d_in[0];
    const int*   ei  = (const int*)d_in[1];
    const float* W1  = (const float*)d_in[2];
    const float* as1 = (const float*)d_in[3];
    const float* ad1 = (const float*)d_in[4];
    const float* b1  = (const float*)d_in[5];
    const float* W2  = (const float*)d_in[6];
    const float* as2 = (const float*)d_in[7];
    const float* ad2 = (const float*)d_in[8];
    const float* b2  = (const float*)d_in[9];
    float* out = (float*)d_out;

    const int N  = in_sizes[0] / 128;
    const int E  = in_sizes[1] / 2;
    const int ET = E + N;

    char* ws = (char*)d_ws;
    size_t off = 0;
    auto alloc = [&](size_t bytes) -> char* {
        char* p = ws + off;
        off = (off + bytes + 255) & ~size_t(255);
        return p;
    };
    _Float16* xh1  = (_Float16*)alloc((size_t)N * 128 * 2);
    _Float16* hbuf = (_Float16*)alloc((size_t)N * 128 * 2);
    _Float16* xh2  = (_Float16*)alloc((size_t)N * 64 * 2);
    float*  a_s1 = (float*)alloc((size_t)N * 2 * 4);
    float*  a_d1 = (float*)alloc((size_t)N * 2 * 4);
    float*  a_s2 = (float*)alloc((size_t)N * 4);
    float*  a_d2 = (float*)alloc((size_t)N * 4);
    int*    deg  = (int*)alloc((size_t)N * 4);
    int*    offs = (int*)alloc((size_t)(N + 1) * 4);
    int*    rank = (int*)alloc((size_t)ET * 4);
    int*    bsum = (int*)alloc(64 * 4);
    int*    csr  = (int*)alloc((size_t)ET * 4);

    hipMemsetAsync(deg, 0, (size_t)N * 4, stream);

    int gE = (ET + 255) / 256;
    k_hist<<<gE, 256, 0, stream>>>(ei + E, E, N, deg, rank);

    int nb = (N + 1023) / 1024;
    k_scan1<<<nb, 1024, 0, stream>>>(deg, offs, bsum, N);
    k_scan2<<<1, 64, 0, stream>>>(bsum, nb);
    k_scan3<<<(N + 1 + 255) / 256, 256, 0, stream>>>(deg, offs, bsum, N, ET);
    k_scatter<<<gE, 256, 0, stream>>>(ei, ei + E, E, N, offs, rank, csr);

    int gN4 = (N + 3) / 4;
    k_gemm1<<<(N + 63) / 64, 256, 0, stream>>>(x, W1, as1, ad1, xh1, a_s1, a_d1, N);
    k_agg1<<<gN4, 256, 0, stream>>>((const __half2*)xh1, a_s1, a_d1, offs, csr, b1,
                                    (__half2*)hbuf, N);
    k_gemm2<<<(N + 63) / 64, 256, 0, stream>>>(hbuf, W2, as2, ad2, xh2, a_s2, a_d2, N);
    k_agg2<<<gN4, 256, 0, stream>>>((const __half*)xh2, a_s2, a_d2, offs, csr, b2, out, N);
}